// Round 4
// baseline (102.817 us; speedup 1.0000x reference)
//
#include <hip/hip_runtime.h>
#include <hip/hip_cooperative_groups.h>
#include <math.h>

namespace cg = cooperative_groups;

#define Bn 16
#define Ln 1444      // 38*38
#define NCn 21
#define Cn 64
#define NBn 23       // ceil(1444/64)
#define KC 1344      // 21*64

// One block per (batch, 64-position tile). Phase 1 -> bs; grid sync; phase 2.
// tile + WS stay live in LDS across the sync (no src/cls round-trips).
__global__ __launch_bounds__(256) void kFused(const float* __restrict__ cls_pred,
                                              const float* __restrict__ source,
                                              const float* __restrict__ R,
                                              float* __restrict__ fused,
                                              float* __restrict__ src_out,
                                              float* __restrict__ bs) {
    cg::grid_group grid = cg::this_grid();
    int b = blockIdx.x / NBn, m = blockIdx.x % NBn;
    int base = m * 64;
    int lane = threadIdx.x & 63, grp = threadIdx.x >> 6;

    __shared__ float tile[64][65];   // tile[c][j], stride-65 => conflict-free both ways
    __shared__ float WS[4][KC];      // per-wave per-class chunk sums (live across sync)
    __shared__ float PS[KC];         // prefix over blocks < m
    __shared__ float Tt[KC];         // batch totals
    __shared__ float Ul[KC];         // [a*64+c] = sum_k R[k][a]*T[k][c]
    __shared__ float Rd[21][22];     // R[a][k]-R[k][a]
    __shared__ float Rl[441];
    __shared__ float Rdg[21];
    __shared__ int cls[64];

    // ---- phase 1a: source tile (coalesced) + R tables ----
#pragma unroll
    for (int cc = 0; cc < 16; cc++) {
        int c = grp * 16 + cc;
        float v = 0.f;
        if (base + lane < Ln) v = source[((size_t)b * Cn + c) * Ln + base + lane];
        tile[c][lane] = v;
    }
    for (int i = threadIdx.x; i < 441; i += 256) {
        float r = R[i];
        Rl[i] = r;
        int aa = i / 21, kk = i % 21;
        Rd[aa][kk] = r - R[kk * 21 + aa];
    }
    if (threadIdx.x < 21) Rdg[threadIdx.x] = R[threadIdx.x * 22];

    // ---- phase 1b: classify (identical math to the passing R3 version) ----
    {
        int p = threadIdx.x >> 2, a = threadIdx.x & 3;
        bool valid = (base + p < Ln);
        const float* q = cls_pred + ((size_t)b * Ln + base + p) * 84 + a * 21;
        float x[21];
#pragma unroll
        for (int i = 0; i < 21; i++) x[i] = valid ? q[i] : 0.f;
        float mx = x[0];
#pragma unroll
        for (int i = 1; i < 21; i++) mx = fmaxf(mx, x[i]);
        float s = 0.f;
#pragma unroll
        for (int i = 0; i < 21; i++) { x[i] = expf(x[i] - mx); s += x[i]; }
        float best = -1.f; int bi = 0;
#pragma unroll
        for (int i = 0; i < 21; i++) {
            float sm = x[i] / s;                     // mimic softmax exp/sum
            if (sm > best) { best = sm; bi = a * 21 + i; }
        }
#pragma unroll
        for (int d = 1; d <= 2; d <<= 1) {
            float ob = __shfl_xor(best, d);
            int oi = __shfl_xor(bi, d);
            if (ob > best || (ob == best && oi < bi)) { best = ob; bi = oi; }
        }
        if (a == 0) cls[p] = valid ? (bi % 21) : 255;
    }
    __syncthreads();

    // ---- phase 1c: write src (B,L,C) coalesced ----
#pragma unroll
    for (int jj = 0; jj < 16; jj++) {
        int j = grp * 16 + jj;
        if (base + j < Ln) src_out[((size_t)b * Ln + base + j) * Cn + lane] = tile[lane][j];
    }

    // ---- phase 1d: per-class register sums of own 16 positions ----
    {
        float cs[21];
#pragma unroll
        for (int k = 0; k < 21; k++) cs[k] = 0.f;
#pragma unroll
        for (int jj = 0; jj < 16; jj++) {
            int j = grp * 16 + jj;
            int k = cls[j];                      // wave-uniform broadcast
            float v = tile[lane][j];
#pragma unroll
            for (int kk = 0; kk < 21; kk++) cs[kk] += (kk == k) ? v : 0.f;
        }
#pragma unroll
        for (int kk = 0; kk < 21; kk++) WS[grp][kk * 64 + lane] = cs[kk];
    }
    __syncthreads();
    for (int i = threadIdx.x; i < KC; i += 256) {
        float v = WS[0][i] + WS[1][i] + WS[2][i] + WS[3][i];
        bs[((size_t)b * NBn + m) * KC + i] = v;
    }

    __threadfence();
    grid.sync();

    // ---- phase 2a: stream batch's bs (float4, 23 independent loads) ----
    for (int g = threadIdx.x; g < KC / 4; g += 256) {
        float rx = 0.f, ry = 0.f, rz = 0.f, rw = 0.f;
        float px = 0.f, py = 0.f, pz = 0.f, pw = 0.f;
#pragma unroll
        for (int mm = 0; mm < NBn; mm++) {
            float4 v = *reinterpret_cast<const float4*>(&bs[((size_t)b * NBn + mm) * KC + g * 4]);
            rx += v.x; ry += v.y; rz += v.z; rw += v.w;
            if (mm < m) { px += v.x; py += v.y; pz += v.z; pw += v.w; }  // uniform branch
        }
        PS[g * 4] = px; PS[g * 4 + 1] = py; PS[g * 4 + 2] = pz; PS[g * 4 + 3] = pw;
        Tt[g * 4] = rx; Tt[g * 4 + 1] = ry; Tt[g * 4 + 2] = rz; Tt[g * 4 + 3] = rw;
    }
    __syncthreads();

    // ---- phase 2b: Ul[a*64+c] = sum_k R[k][a] * T[k][c] ----
    for (int p = threadIdx.x; p < KC; p += 256) {
        int aa = p >> 6, c = p & 63;
        float u = 0.f;
#pragma unroll
        for (int k = 0; k < 21; k++) u += Rl[k * 21 + aa] * Tt[k * 64 + c];
        Ul[p] = u;
    }
    __syncthreads();

    // ---- phase 2c: register running sums + final combine ----
    float ms[21];
#pragma unroll
    for (int k = 0; k < 21; k++) {
        float x = PS[k * 64 + lane];
#pragma unroll
        for (int g = 0; g < 3; g++)
            if (g < grp) x += WS[g][k * 64 + lane];
        ms[k] = x;
    }
    int nvalid = (Ln - base < 64) ? (Ln - base) : 64;
    for (int t = 0; t < 16; t++) {
        int i = grp * 16 + t;
        if (i >= nvalid) break;
        int ci = cls[i];                          // wave-uniform
        float sv = tile[lane][i];                 // conflict-free
        float acc = Ul[ci * 64 + lane] + (((ci != 0) ? 1.f : 0.f) - Rdg[ci]) * sv;
#pragma unroll
        for (int k = 0; k < 21; k++) acc += Rd[ci][k] * ms[k];
        fused[((size_t)b * Ln + base + i) * Cn + lane] = acc;
#pragma unroll
        for (int kk = 0; kk < 21; kk++) ms[kk] += (kk == ci) ? sv : 0.f;
    }
}

extern "C" void kernel_launch(void* const* d_in, const int* in_sizes, int n_in,
                              void* d_out, int out_size, void* d_ws, size_t ws_size,
                              hipStream_t stream) {
    const float* cls_pred = (const float*)d_in[0];
    const float* source = (const float*)d_in[1];
    const float* cls_r_prob = (const float*)d_in[2];

    float* fused = (float*)d_out;
    float* src_out = fused + (size_t)Bn * Ln * Cn;
    float* bs = (float*)d_ws;                    // 16*23*1344*4 = 1.98 MB

    void* args[] = { (void*)&cls_pred, (void*)&source, (void*)&cls_r_prob,
                     (void*)&fused, (void*)&src_out, (void*)&bs };
    hipLaunchCooperativeKernel((const void*)kFused, dim3(Bn * NBn), dim3(256),
                               args, 0, stream);
}